// Round 14
// baseline (249.636 us; speedup 1.0000x reference)
//
#include <hip/hip_runtime.h>
#include <hip/hip_bf16.h>
#include <stdint.h>

#define B_ 4
#define L_ 4096
#define D_ 1024
#define H_ 16
#define E_ 64
#define M_ (B_*L_)       // 16384 rows
#define N1_ (3*D_)       // 3072
#define CHK 128
#define NC (L_/CHK)      // 32
#define BH (B_*H_)       // 64

#define EPS_FEAT 1.0001f
#define EPS_DEN 1e-6f

typedef __attribute__((ext_vector_type(4))) float f32x4;
typedef __attribute__((ext_vector_type(8))) short bf16x8;

__device__ __forceinline__ unsigned short f2bf(float x) {
    union { float f; unsigned int u; } v; v.f = x;
    unsigned int r = v.u + 0x7FFFu + ((v.u >> 16) & 1u);
    return (unsigned short)(r >> 16);
}

// async global->LDS, 16B per lane. LDS dest = wave-uniform base + lane*16.
__device__ __forceinline__ void gload_lds16(const unsigned short* g, unsigned short* l) {
    __builtin_amdgcn_global_load_lds(
        (const __attribute__((address_space(1))) unsigned int*)(const void*)g,
        (__attribute__((address_space(3))) unsigned int*)(void*)l,
        16, 0, 0);
}

// ---------------- prep: both W transposes (x-cvt fused into gemm<0>) ----------------

__global__ __launch_bounds__(256) void prep(const float* __restrict__ W0,
                                            const float* __restrict__ W1,
                                            unsigned short* __restrict__ T0,
                                            unsigned short* __restrict__ T1) {
    __shared__ float tile[32][33];
    int bid = blockIdx.x, t = threadIdx.x;
    const float* W; unsigned short* WT; int N, nb, kb;
    if (bid < 3072) {
        W = W0; WT = T0; N = N1_;                 // Wqkv: 96 x 32 tiles
        nb = (bid % 96) * 32; kb = (bid / 96) * 32;
    } else {
        int idx = bid - 3072;                     // Wout: 32 x 32 tiles
        W = W1; WT = T1; N = D_;
        nb = (idx % 32) * 32; kb = (idx / 32) * 32;
    }
    int tx = t & 31, ty = t >> 5;                 // ty 0..7
#pragma unroll
    for (int j = 0; j < 4; ++j)
        tile[ty + 8*j][tx] = W[(size_t)(kb + ty + 8*j) * N + nb + tx];
    __syncthreads();
#pragma unroll
    for (int j = 0; j < 4; ++j) {
        int nl = ty + 8*j;
        WT[(size_t)(nb + nl) * D_ + kb + tx] = f2bf(tile[tx][nl]);
    }
}

// ---------------- 128x256 pipelined GEMM ----------------
// BK=32, 3-slot LDS ring (72 KB) -> 2 blocks/CU, 4 waves, 16x16x32 MFMA.
// MODE 0: A = x (f32), reg-staged with fused f32->bf16 cvt (4 gl_dwordx4 ->
//   cvt -> 2 ds_write_b128 to swizzled LDS). B = WqT bf16 via global_load_lds.
//   Schedule: tile T = [frags(T); writeA(T+2) (regs from T-1); loadA(T+3);
//   stageB(T+2); barrier; lgkm(0); MFMA]. writeA target slot (T+2)%3=(T-1)%3:
//   its readers drained at T-1 in-tile lgkm, T-1 boundary barrier precedes -> WAR ok.
//   Boundary vmcnt(8): loads newer than B(T+1) = A(T+3)4 + B(T+2)4 = 8
//   (A(T+2) regs force-drained earlier by compiler wait before writeA). Tails:
//   T=NT-3 vmcnt(4), T=NT-2 vmcnt(0).
// MODE 1: A = attn bf16, both A and B via global_load_lds (R12 structure,
//   6 chunks/tile, boundary vmcnt(6), tail vmcnt(0)).

template<int MODE, int KDIM, int NDIM>
__global__ __launch_bounds__(256, 2) void gemm128(
    const void* __restrict__ Araw,
    const unsigned short* __restrict__ BT,
    const float* __restrict__ bias,
    float* __restrict__ outF,
    unsigned short* __restrict__ qf,
    unsigned short* __restrict__ kf,
    unsigned short* __restrict__ vf)
{
    __shared__ __align__(16) unsigned short smem[36864];   // 3 x (A 8KB | B 16KB)

    const int t = threadIdx.x, lane = t & 63, w = t >> 6;   // 4 waves, w = n-slice

    const int nwgx = NDIM / 256;
    const int nwg = nwgx * (M_ / 128);
    const int bid0 = blockIdx.y * nwgx + blockIdx.x;
    const int swz = (bid0 & 7) * (nwg >> 3) + (bid0 >> 3);
    const int m0 = (swz / nwgx) * 128, n0 = (swz % nwgx) * 256;
    const int lr = lane & 15, lg = lane >> 4;

    const float* Af = (const float*)Araw;               // MODE 0
    const unsigned short* Ab16 = (const unsigned short*)Araw;  // MODE 1

    auto stageB = [&](int T) {
        unsigned short* bb = smem + (T % 3) * 12288 + 4096;
        const int kt = T * 32;
#pragma unroll
        for (int i = 0; i < 4; ++i) {                      // B: 256x32, 4 chunks/thr
            int c = i * 256 + t;
            int row = c >> 2, s = c & 3;
            int col = ((s ^ ((row >> 1) & 3)) << 3);
            gload_lds16(BT + (size_t)(n0 + row) * KDIM + kt + col, &bb[c * 8]);
        }
    };
    auto stageA1 = [&](int T) {                            // MODE 1 A path
        unsigned short* base = smem + (T % 3) * 12288;
        const int kt = T * 32;
#pragma unroll
        for (int i = 0; i < 2; ++i) {
            int c = i * 256 + t;
            int row = c >> 2, s = c & 3;
            int col = ((s ^ ((row >> 1) & 3)) << 3);
            gload_lds16(Ab16 + (size_t)(m0 + row) * KDIM + kt + col, &base[c * 8]);
        }
    };

    uint4 areg[4];                                         // MODE 0: 2 chunks f32
    auto loadA0 = [&](int T) {
        const int kt = T * 32;
#pragma unroll
        for (int i = 0; i < 2; ++i) {
            int c = i * 256 + t;
            int row = c >> 2, s = c & 3;
            const float* src = Af + (size_t)(m0 + row) * KDIM + kt + s * 8;
            areg[i*2]   = *(const uint4*)src;
            areg[i*2+1] = *(const uint4*)(src + 4);
        }
    };
    auto writeA0 = [&](int T) {
        unsigned short* base = smem + (T % 3) * 12288;
#pragma unroll
        for (int i = 0; i < 2; ++i) {
            int c = i * 256 + t;
            int row = c >> 2, s = c & 3;
            int slot = s ^ ((row >> 1) & 3);
            const float* f = (const float*)&areg[i * 2];
            uint4 wv;
            wv.x = (unsigned int)f2bf(f[0]) | ((unsigned int)f2bf(f[1]) << 16);
            wv.y = (unsigned int)f2bf(f[2]) | ((unsigned int)f2bf(f[3]) << 16);
            wv.z = (unsigned int)f2bf(f[4]) | ((unsigned int)f2bf(f[5]) << 16);
            wv.w = (unsigned int)f2bf(f[6]) | ((unsigned int)f2bf(f[7]) << 16);
            *(uint4*)&base[row * 32 + slot * 8] = wv;
        }
    };

    f32x4 acc[8][4] = {};

    auto mfma_phase = [&](int T) {
        const unsigned short* Ab = smem + (T % 3) * 12288;
        const unsigned short* Bb = Ab + 4096;
        bf16x8 af[8], bq[4];
#pragma unroll
        for (int m = 0; m < 8; ++m) {
            int row = m * 16 + lr;
            int slot = lg ^ ((row >> 1) & 3);
            af[m] = *(const bf16x8*)&Ab[row * 32 + slot * 8];
        }
#pragma unroll
        for (int n = 0; n < 4; ++n) {
            int row = w * 64 + n * 16 + lr;
            int slot = lg ^ ((row >> 1) & 3);
            bq[n] = *(const bf16x8*)&Bb[row * 32 + slot * 8];
        }
        return [=, &acc]() mutable {};    // unused; kept simple below
    };
    (void)mfma_phase;

    constexpr int NT = KDIM / 32;                 // 32

    // unified per-tile compute (frag reads + staged work + MFMA)
    auto tile = [&](int T, bool wA, bool lA, bool sB) {
        const unsigned short* Ab = smem + (T % 3) * 12288;
        const unsigned short* Bb = Ab + 4096;
        bf16x8 af[8], bq[4];
#pragma unroll
        for (int m = 0; m < 8; ++m) {
            int row = m * 16 + lr;
            int slot = lg ^ ((row >> 1) & 3);
            af[m] = *(const bf16x8*)&Ab[row * 32 + slot * 8];
        }
#pragma unroll
        for (int n = 0; n < 4; ++n) {
            int row = w * 64 + n * 16 + lr;
            int slot = lg ^ ((row >> 1) & 3);
            bq[n] = *(const bf16x8*)&Bb[row * 32 + slot * 8];
        }
        if (MODE == 0) {
            if (wA) writeA0(T + 2);
            if (lA) loadA0(T + 3);
            if (sB) stageB(T + 2);
        } else {
            if (sB) { stageA1(T + 2); stageB(T + 2); }
        }
        __builtin_amdgcn_s_barrier();
        asm volatile("s_waitcnt lgkmcnt(0)" ::: "memory");
        __builtin_amdgcn_sched_barrier(0);
        __builtin_amdgcn_s_setprio(1);
#pragma unroll
        for (int m = 0; m < 8; ++m)
#pragma unroll
            for (int n = 0; n < 4; ++n)
                acc[m][n] = __builtin_amdgcn_mfma_f32_16x16x32_bf16(af[m], bq[n], acc[m][n], 0, 0, 0);
        __builtin_amdgcn_s_setprio(0);
    };

    if (MODE == 0) {
        loadA0(0); writeA0(0);
        loadA0(1); writeA0(1);
        loadA0(2);                         // regs for writeA(2) at T=0
        stageB(0); stageB(1);
        asm volatile("s_waitcnt vmcnt(0)" ::: "memory");
        __builtin_amdgcn_s_barrier();
        __builtin_amdgcn_sched_barrier(0);
        for (int T = 0; T <= NT - 4; ++T) {
            tile(T, true, true, true);
            asm volatile("s_waitcnt vmcnt(8)" ::: "memory");
            __builtin_amdgcn_s_barrier();
            __builtin_amdgcn_sched_barrier(0);
        }
        tile(NT - 3, true, false, true);
        asm volatile("s_waitcnt vmcnt(4)" ::: "memory");
        __builtin_amdgcn_s_barrier();
        __builtin_amdgcn_sched_barrier(0);
        tile(NT - 2, false, false, false);
        asm volatile("s_waitcnt vmcnt(0)" ::: "memory");
        __builtin_amdgcn_s_barrier();
        __builtin_amdgcn_sched_barrier(0);
        tile(NT - 1, false, false, false);
    } else {
        stageA1(0); stageB(0);
        stageA1(1); stageB(1);
        asm volatile("s_waitcnt vmcnt(6)" ::: "memory");   // tile 0 landed
        __builtin_amdgcn_s_barrier();
        __builtin_amdgcn_sched_barrier(0);
        for (int T = 0; T < NT - 2; ++T) {
            tile(T, false, false, true);
            asm volatile("s_waitcnt vmcnt(6)" ::: "memory");
            __builtin_amdgcn_s_barrier();
            __builtin_amdgcn_sched_barrier(0);
        }
        tile(NT - 2, false, false, false);
        asm volatile("s_waitcnt vmcnt(0)" ::: "memory");
        __builtin_amdgcn_s_barrier();
        __builtin_amdgcn_sched_barrier(0);
        tile(NT - 1, false, false, false);
    }
    __syncthreads();                                     // LDS reuse below

    // ---------------- epilogues (LDS-routed, coalesced stores) ----------------
    if (MODE == 0) {
        unsigned short* cbf = smem;                      // [128][264] bf16, one pass
        const bool isQ = (n0 < D_), isK = (n0 >= D_ && n0 < 2*D_);
        const float scale = isQ ? 0.125f : 1.0f;
        unsigned short* buf = isQ ? qf : (isK ? kf : vf);
        const int b = m0 >> 12, l0 = m0 & 4095;
        const int h0 = (n0 & 1023) >> 6;
#pragma unroll
        for (int n = 0; n < 4; ++n) {
            int cl = w*64 + n*16 + lr;
            float bv = bias[n0 + cl];
#pragma unroll
            for (int m = 0; m < 8; ++m)
#pragma unroll
                for (int q = 0; q < 4; ++q) {
                    int rl = m*16 + lg*4 + q;
                    float val = (acc[m][n][q] + bv) * scale;
                    float fv = (isQ || isK)
                               ? ((val > 0.f ? val : __expf(val) - 1.f) + EPS_FEAT)
                               : val;
                    cbf[rl * 264 + cl] = f2bf(fv);
                }
        }
        __syncthreads();
#pragma unroll
        for (int hh = 0; hh < 4; ++hh) {
            unsigned short* dst = buf + (((size_t)(b * H_ + h0 + hh)) * L_ + l0) * E_;
#pragma unroll
            for (int i = 0; i < 4; ++i) {
                int c = i*256 + t, row = c >> 3, ch = c & 7;
                uint4 v = *(const uint4*)&cbf[row * 264 + hh*64 + ch*8];
                *(uint4*)&dst[row * 64 + ch*8] = v;
            }
        }
    } else {
        float* cfl = (float*)smem;                       // [64][260] f32, 2 passes
#pragma unroll
        for (int p = 0; p < 2; ++p) {
#pragma unroll
            for (int n = 0; n < 4; ++n) {
                int cl = w*64 + n*16 + lr;
                float bv = bias[n0 + cl];
#pragma unroll
                for (int mm = 0; mm < 4; ++mm)
#pragma unroll
                    for (int q = 0; q < 4; ++q) {
                        int rl = mm*16 + lg*4 + q;
                        cfl[rl * 260 + cl] = acc[p*4 + mm][n][q] + bv;
                    }
            }
            __syncthreads();
#pragma unroll
            for (int i = 0; i < 16; ++i) {
                int c = i*256 + t, row = c >> 6, ch = c & 63;
                float4 v = *(const float4*)&cfl[row * 260 + ch*4];
                *(float4*)&outF[(size_t)(m0 + p*64 + row) * NDIM + n0 + ch*4] = v;
            }
            __syncthreads();
        }
    }
}

// ---------------- chunk KV (TRANSPOSED state): KVT_c[f][e] = sum_l V[l][f] K[l][e] ----------------

__global__ __launch_bounds__(256) void chunk_kv(
    const unsigned short* __restrict__ kf, const unsigned short* __restrict__ vf,
    unsigned short* __restrict__ kvout, float* __restrict__ ksout)
{
    constexpr int LDK = 136;                 // 128 + 8 pad
    __shared__ unsigned short Kt[64 * LDK];  // K^T : [e][l]
    __shared__ unsigned short Vt[80 * LDK];  // V^T : [f][l], row 64 = ones

    int t = threadIdx.x, lane = t & 63, w = t >> 6;
    int bid = blockIdx.x;                    // bh*NC + c
    const unsigned short* kp = kf + (size_t)bid * CHK * E_;
    const unsigned short* vp = vf + (size_t)bid * CHK * E_;

#pragma unroll
    for (int it = 0; it < 4; ++it) {
        int s = it * 256 + t;
        int rl = s >> 3, e0 = (s & 7) << 3;
        uint4 kv8 = *(const uint4*)(kp + s * 8);
        uint4 vv8 = *(const uint4*)(vp + s * 8);
        unsigned int kw[4] = {kv8.x, kv8.y, kv8.z, kv8.w};
        unsigned int vw[4] = {vv8.x, vv8.y, vv8.z, vv8.w};
#pragma unroll
        for (int jw = 0; jw < 4; ++jw) {
            Kt[(e0 + 2*jw    ) * LDK + rl] = (unsigned short)(kw[jw] & 0xFFFF);
            Kt[(e0 + 2*jw + 1) * LDK + rl] = (unsigned short)(kw[jw] >> 16);
            Vt[(e0 + 2*jw    ) * LDK + rl] = (unsigned short)(vw[jw] & 0xFFFF);
            Vt[(e0 + 2*jw + 1) * LDK + rl] = (unsigned short)(vw[jw] >> 16);
        }
    }
    if (t < 128) Vt[64 * LDK + t] = 0x3F80;  // bf16 1.0
    for (int i = t; i < 15 * LDK; i += 256) Vt[65 * LDK + i] = 0;
    __syncthreads();

    int lr = lane & 15, lg = lane >> 4;
    f32x4 acc[4] = {};
    f32x4 accE[4] = {};
#pragma unroll
    for (int ks = 0; ks < 4; ++ks) {
        bf16x8 a = *(const bf16x8*)&Vt[(w*16 + lr) * LDK + ks*32 + lg*8];
#pragma unroll
        for (int n = 0; n < 4; ++n) {
            bf16x8 b = *(const bf16x8*)&Kt[(n*16 + lr) * LDK + ks*32 + lg*8];
            acc[n] = __builtin_amdgcn_mfma_f32_16x16x32_bf16(a, b, acc[n], 0, 0, 0);
        }
    }
    if (w == 0) {
#pragma unroll
        for (int ks = 0; ks < 4; ++ks) {
            bf16x8 a = *(const bf16x8*)&Vt[(64 + lr) * LDK + ks*32 + lg*8];
#pragma unroll
            for (int n = 0; n < 4; ++n) {
                bf16x8 b = *(const bf16x8*)&Kt[(n*16 + lr) * LDK + ks*32 + lg*8];
                accE[n] = __builtin_amdgcn_mfma_f32_16x16x32_bf16(a, b, accE[n], 0, 0, 0);
            }
        }
    }
    unsigned short* kvo = kvout + (size_t)bid * E_ * E_;   // [f][e]
#pragma unroll
    for (int n = 0; n < 4; ++n)
#pragma unroll
        for (int q = 0; q < 4; ++q) {
            int f = w*16 + lg*4 + q, e = n*16 + lr;
            kvo[f * 64 + e] = f2bf(acc[n][q]);
        }
    if (w == 0 && lg == 0) {
#pragma unroll
        for (int n = 0; n < 4; ++n)
            ksout[(size_t)bid * 64 + n*16 + lr] = accE[n][0];
    }
}

// ---------------- exclusive prefix over chunks (per bh), bf16 in/out ----------------

__global__ __launch_bounds__(256) void prefix_kv(
    const uint2* __restrict__ kvin, const float* __restrict__ ks,
    uint2* __restrict__ kvb, unsigned short* __restrict__ ksb)
{
    int bh = blockIdx.y, part = blockIdx.x, t = threadIdx.x;
    int idx = part * 256 + t;
    float st0 = 0.f, st1 = 0.f, st2 = 0.f, st3 = 0.f;
    for (int c = 0; c < NC; ++c) {
        size_t o = ((size_t)bh * NC + c) * 1024 + idx;
        uint2 tmp = kvin[o];
        kvb[o] = make_uint2(
            (unsigned int)f2bf(st0) | ((unsigned int)f2bf(st1) << 16),
            (unsigned int)f2bf(st2) | ((unsigned int)f2bf(st3) << 16));
        union { unsigned int u; float f; } cv;
        cv.u = (tmp.x & 0xFFFFu) << 16; st0 += cv.f;
        cv.u = tmp.x & 0xFFFF0000u;     st1 += cv.f;
        cv.u = (tmp.y & 0xFFFFu) << 16; st2 += cv.f;
        cv.u = tmp.y & 0xFFFF0000u;     st3 += cv.f;
    }
    if (part == 0 && t < 64) {
        float s0 = 0.f;
        for (int c = 0; c < NC; ++c) {
            float tmp = ks[((size_t)bh * NC + c) * 64 + t];
            ksb[((size_t)bh * NC + c) * 64 + t] = f2bf(s0);
            s0 += tmp;
        }
    }
}

// ---------------- attention output per (bh, chunk) ----------------

__global__ __launch_bounds__(256, 2) void attn_out(
    const unsigned short* __restrict__ qf, const unsigned short* __restrict__ kf,
    const unsigned short* __restrict__ vf, const unsigned short* __restrict__ kvb,
    const unsigned short* __restrict__ ksb, unsigned short* __restrict__ attn)
{
    constexpr int LK = 72;
    constexpr int LV = 136;
    __shared__ unsigned short Ks[128 * LK];
    __shared__ unsigned short Vt[64 * LV];
    __shared__ unsigned short Ss[128 * LV];

    int t = threadIdx.x, lane = t & 63, w = t >> 6;
    int bid = blockIdx.x;
    int bh = bid >> 5, c = bid & 31;
    const unsigned short* qp = qf + (size_t)bid * CHK * E_;
    const unsigned short* kp = kf + (size_t)bid * CHK * E_;
    const unsigned short* vp = vf + (size_t)bid * CHK * E_;
    const unsigned short* kvp = kvb + (size_t)bid * 4096;   // [f][e]

    int lr = lane & 15, lg = lane >> 4;
    const int jsel[2] = {w, 7 - w};

    bf16x8 aq[2][2];
#pragma unroll
    for (int mi = 0; mi < 2; ++mi)
#pragma unroll
        for (int ks = 0; ks < 2; ++ks)
            aq[mi][ks] = *(const bf16x8*)(qp + (jsel[mi]*16 + lr) * 64 + ks*32 + lg*8);

#pragma unroll
    for (int it = 0; it < 4; ++it) {
        int s = it * 256 + t;
        int r = s >> 3, e0 = (s & 7) << 3;
        uint4 kv = *(const uint4*)(kp + s * 8);
        uint4 vv = *(const uint4*)(vp + s * 8);
        *(uint4*)&Ks[r * LK + e0] = kv;
        unsigned int vw[4] = {vv.x, vv.y, vv.z, vv.w};
#pragma unroll
        for (int jw = 0; jw < 4; ++jw) {
            Vt[(e0 + 2*jw    ) * LV + r] = (unsigned short)(vw[jw] & 0xFFFF);
            Vt[(e0 + 2*jw + 1) * LV + r] = (unsigned short)(vw[jw] >> 16);
        }
    }
    bf16x8 zfrag = {0,0,0,0,0,0,0,0};
    bf16x8 bone = zfrag, bks[2] = {zfrag, zfrag};
    if (lr == 0) {
#pragma unroll
        for (int j = 0; j < 8; ++j) bone[j] = (short)0x3F80;
        bks[0] = *(const bf16x8*)&ksb[(size_t)bid * 64 + lg*8];
        bks[1] = *(const bf16x8*)&ksb[(size_t)bid * 64 + 32 + lg*8];
    }
    __syncthreads();

#pragma unroll
    for (int mi = 0; mi < 2; ++mi) {
        int j = jsel[mi];
        int rbase = j * 16;
        int jbmax = j | 1;
        for (int jb = 0; jb <= jbmax; ++jb) {
            if (jb <= j) {
                f32x4 sacc = {};
                bf16x8 b0 = *(const bf16x8*)&Ks[(jb*16 + lr) * LK + lg*8];
                bf16x8 b1 = *(const bf16x8*)&Ks[(jb*16 + lr) * LK + 32 + lg*8];
                sacc = __builtin_amdgcn_mfma_f32_16x16x32_bf16(aq[mi][0], b0, sacc, 0, 0, 0);
                sacc = __builtin_amdgcn_mfma_f32_16x16x32_bf16(aq[mi][1], b1, sacc, 0, 0, 0);
#pragma unroll
                for (int q = 0; q < 4; ++q) {
                    int r = rbase + lg*4 + q;
                    int jj = jb*16 + lr;
                    Ss[r * LV + jj] = (jj <= r) ? f2bf(sacc[q]) : (unsigned short)0;
                }
            } else {
#pragma unroll
                for (int q = 0; q < 4; ++q) {
                    int r = rbase + lg*4 + q;
                    Ss[r * LV + jb*16 + lr] = 0;
                }
            }
        }
    }

    f32x4 oacc[2][5] = {};
#pragma unroll
    for (int mi = 0; mi < 2; ++mi) {
        int j = jsel[mi];
        int rbase = j * 16;
#pragma unroll
        for (int ks = 0; ks < 2; ++ks) {
            bf16x8 a = aq[mi][ks];
#pragma unroll
            for (int n = 0; n < 4; ++n) {
                bf16x8 b = *(const bf16x8*)&kvp[(n*16 + lr) * 64 + ks*32 + lg*8];
                oacc[mi][n] = __builtin_amdgcn_mfma_f32_16x16x32_bf16(a, b, oacc[mi][n], 0, 0, 0);
            }
            oacc[mi][4] = __builtin_amdgcn_mfma_f32_16x16x32_bf16(a, bks[ks], oacc[mi][4], 0, 0, 0);
        }
        for (int ks = 0; ks <= (j >> 1); ++ks) {
            bf16x8 a = *(const bf16x8*)&Ss[(rbase + lr) * LV + ks*32 + lg*8];
#pragma unroll
            for (int n = 0; n < 4; ++n) {
                bf16x8 b = *(const bf16x8*)&Vt[(n*16 + lr) * LV + ks*32 + lg*8];
                oacc[mi][n] = __builtin_amdgcn_mfma_f32_16x16x32_bf16(a, b, oacc[mi][n], 0, 0, 0);
            }
            oacc[mi][4] = __builtin_amdgcn_mfma_f32_16x16x32_bf16(a, bone, oacc[mi][4], 0, 0, 0);
        }
    }

    int b_idx = bh >> 4, h_idx = bh & 15;
#pragma unroll
    for (int mi = 0; mi < 2; ++mi) {
        int rbase = jsel[mi] * 16;
        float den[4];
#pragma unroll
        for (int q = 0; q < 4; ++q)
            den[q] = __shfl(oacc[mi][4][q], lane & 48, 64) + EPS_DEN;
#pragma unroll
        for (int n = 0; n < 4; ++n) {
#pragma unroll
            for (int q = 0; q < 4; ++q) {
                int r = rbase + lg*4 + q;
                int lpos = c * CHK + r;
                int col = n*16 + lr;
                size_t dst = ((size_t)b_idx * L_ + lpos) * D_ + h_idx * 64 + col;
                attn[dst] = f2bf(oacc[mi][n][q] / den[q]);
            }
        }
    }
}

// ---------------- launcher ----------------

extern "C" void kernel_launch(void* const* d_in, const int* in_sizes, int n_in,
                              void* d_out, int out_size, void* d_ws, size_t ws_size,
                              hipStream_t stream)
{
    const float* x    = (const float*)d_in[0];
    const float* Wqkv = (const float*)d_in[1];
    const float* bqkv = (const float*)d_in[2];
    const float* Wout = (const float*)d_in[3];
    const float* bout = (const float*)d_in[4];
    float* out = (float*)d_out;

    char* ws = (char*)d_ws;
    size_t off = 0;
    auto alloc = [&](size_t bytes) { void* p = ws + off; off += (bytes + 255) & ~(size_t)255; return p; };
    unsigned short* WqT = (unsigned short*)alloc((size_t)N1_ * D_ * 2);
    unsigned short* WoT = (unsigned short*)alloc((size_t)D_ * D_ * 2);
    unsigned short* qfb = (unsigned short*)alloc((size_t)M_ * D_ * 2);
    unsigned short* kfb = (unsigned short*)alloc((size_t)M_ * D_ * 2);
    unsigned short* vfb = (unsigned short*)alloc((size_t)M_ * D_ * 2);
    unsigned short* kvw = (unsigned short*)alloc((size_t)BH * NC * E_ * E_ * 2);
    float* ksw = (float*)alloc((size_t)BH * NC * E_ * 4);
    unsigned short* kvb = (unsigned short*)alloc((size_t)BH * NC * E_ * E_ * 2);
    unsigned short* ksb = (unsigned short*)alloc((size_t)BH * NC * E_ * 2);
    unsigned short* attn = (unsigned short*)alloc((size_t)M_ * D_ * 2);

    prep<<<3072 + 1024, 256, 0, stream>>>(Wqkv, Wout, WqT, WoT);

    gemm128<0, D_, N1_><<<dim3(N1_ / 256, M_ / 128), 256, 0, stream>>>(
        x, WqT, bqkv, nullptr, qfb, kfb, vfb);

    chunk_kv<<<BH * NC, 256, 0, stream>>>(kfb, vfb, kvw, ksw);
    prefix_kv<<<dim3(4, BH), 256, 0, stream>>>((const uint2*)kvw, ksw, (uint2*)kvb, ksb);
    attn_out<<<BH * NC, 256, 0, stream>>>(qfb, kfb, vfb, kvb, ksb, attn);

    gemm128<1, D_, D_><<<dim3(D_ / 256, M_ / 128), 256, 0, stream>>>(
        attn, WoT, bout, out, nullptr, nullptr, nullptr);
}

// Round 15
// 234.775 us; speedup vs baseline: 1.0633x; 1.0633x over previous
//
#include <hip/hip_runtime.h>
#include <hip/hip_bf16.h>
#include <stdint.h>

#define B_ 4
#define L_ 4096
#define D_ 1024
#define H_ 16
#define E_ 64
#define M_ (B_*L_)       // 16384 rows
#define N1_ (3*D_)       // 3072
#define CHK 128
#define NC (L_/CHK)      // 32
#define BH (B_*H_)       // 64

#define EPS_FEAT 1.0001f
#define EPS_DEN 1e-6f

typedef __attribute__((ext_vector_type(4))) float f32x4;
typedef __attribute__((ext_vector_type(8))) short bf16x8;

__device__ __forceinline__ unsigned short f2bf(float x) {
    union { float f; unsigned int u; } v; v.f = x;
    unsigned int r = v.u + 0x7FFFu + ((v.u >> 16) & 1u);
    return (unsigned short)(r >> 16);
}

// async global->LDS, 16B per lane. LDS dest = wave-uniform base + lane*16.
__device__ __forceinline__ void gload_lds16(const unsigned short* g, unsigned short* l) {
    __builtin_amdgcn_global_load_lds(
        (const __attribute__((address_space(1))) unsigned int*)(const void*)g,
        (__attribute__((address_space(3))) unsigned int*)(void*)l,
        16, 0, 0);
}

// ---------------- prep: x->bf16 (blocks 0..16383) + both W transposes ----------------

__global__ __launch_bounds__(256) void prep(const float* __restrict__ x,
                                            const float* __restrict__ W0,
                                            const float* __restrict__ W1,
                                            unsigned short* __restrict__ xb,
                                            unsigned short* __restrict__ T0,
                                            unsigned short* __restrict__ T1) {
    __shared__ float tile[32][33];
    int bid = blockIdx.x, t = threadIdx.x;
    if (bid < 16384) {
        int i4 = bid * 256 + t;
        float4 v = ((const float4*)x)[i4];
        unsigned int lo = (unsigned int)f2bf(v.x) | ((unsigned int)f2bf(v.y) << 16);
        unsigned int hi = (unsigned int)f2bf(v.z) | ((unsigned int)f2bf(v.w) << 16);
        ((uint2*)xb)[i4] = make_uint2(lo, hi);
        return;
    }
    const float* W; unsigned short* WT; int N, nb, kb;
    if (bid < 16384 + 3072) {
        int idx = bid - 16384;             // Wqkv: 96 x 32
        W = W0; WT = T0; N = N1_;
        nb = (idx % 96) * 32; kb = (idx / 96) * 32;
    } else {
        int idx = bid - 16384 - 3072;      // Wout: 32 x 32
        W = W1; WT = T1; N = D_;
        nb = (idx % 32) * 32; kb = (idx / 32) * 32;
    }
    int tx = t & 31, ty = t >> 5;          // ty 0..7
#pragma unroll
    for (int j = 0; j < 4; ++j)
        tile[ty + 8*j][tx] = W[(size_t)(kb + ty + 8*j) * N + nb + tx];
    __syncthreads();
#pragma unroll
    for (int j = 0; j < 4; ++j) {
        int nl = ty + 8*j;
        WT[(size_t)(nb + nl) * D_ + kb + tx] = f2bf(tile[tx][nl]);
    }
}

// ---------------- 128x256 pipelined GEMM (A bf16 MxK, BT bf16 NxK) ----------------
// BK=32, 3-slot LDS ring (72 KB) -> 2 blocks/CU, 4 waves (256 thr), counted
// vmcnt(6)/tile, slot swizzle lg^((row>>1)&3) (2-way = free).
// Per wave: all 128 A-rows x own 64 B-cols -> acc[8][4], 32 MFMA + 12 b128/tile.
// Ring WAR: stage(T+2) targets slot (T+2)%3 == (T-1)%3; tile T-1's reads were
//   lgkm-awaited at T-1's in-tile barrier, which precedes the T-1 boundary
//   barrier, which precedes stage issue at tile T -> safe.
// vmcnt ledger (6 loads/thread/tile): start of T: T+1 in flight (6). During T:
//   +stage(T+2) = 12. Boundary vmcnt(6) retires T+1 -> landed. Prologue:
//   stage(0),stage(1), vmcnt(6) -> T0 landed. Tail: vmcnt(0) before NT-1.

template<int MODE, int KDIM, int NDIM>
__global__ __launch_bounds__(256, 2) void gemm128(
    const unsigned short* __restrict__ A,
    const unsigned short* __restrict__ BT,
    const float* __restrict__ bias,
    float* __restrict__ outF,
    unsigned short* __restrict__ qf,
    unsigned short* __restrict__ kf,
    unsigned short* __restrict__ vf)
{
    __shared__ __align__(16) unsigned short smem[36864];   // 3 x (A 8KB | B 16KB) = 72 KB

    const int t = threadIdx.x, lane = t & 63, w = t >> 6;   // 4 waves, w = n-slice

    // XCD-chunked bijective swizzle (nwg % 8 == 0 for both modes)
    const int nwgx = NDIM / 256;
    const int nwg = nwgx * (M_ / 128);
    const int bid0 = blockIdx.y * nwgx + blockIdx.x;
    const int swz = (bid0 & 7) * (nwg >> 3) + (bid0 >> 3);
    const int m0 = (swz / nwgx) * 128, n0 = (swz % nwgx) * 256;
    const int lr = lane & 15, lg = lane >> 4;

    auto stage = [&](int T) {
        unsigned short* base = smem + (T % 3) * 12288;
        const int kt = T * 32;
#pragma unroll
        for (int i = 0; i < 2; ++i) {                      // A: 128x32, 2 chunks/thr
            int c = i * 256 + t;
            int row = c >> 2, s = c & 3;
            int col = ((s ^ ((row >> 1) & 3)) << 3);
            gload_lds16(A + (size_t)(m0 + row) * KDIM + kt + col, &base[c * 8]);
        }
        unsigned short* bb = base + 4096;
#pragma unroll
        for (int i = 0; i < 4; ++i) {                      // B: 256x32, 4 chunks/thr
            int c = i * 256 + t;
            int row = c >> 2, s = c & 3;
            int col = ((s ^ ((row >> 1) & 3)) << 3);
            gload_lds16(BT + (size_t)(n0 + row) * KDIM + kt + col, &bb[c * 8]);
        }
    };

    f32x4 acc[8][4] = {};

    auto tile = [&](int T, bool s1) {
        const unsigned short* Ab = smem + (T % 3) * 12288;
        const unsigned short* Bb = Ab + 4096;
        bf16x8 af[8], bq[4];
#pragma unroll
        for (int m = 0; m < 8; ++m) {
            int row = m * 16 + lr;
            int slot = lg ^ ((row >> 1) & 3);
            af[m] = *(const bf16x8*)&Ab[row * 32 + slot * 8];
        }
#pragma unroll
        for (int n = 0; n < 4; ++n) {
            int row = w * 64 + n * 16 + lr;
            int slot = lg ^ ((row >> 1) & 3);
            bq[n] = *(const bf16x8*)&Bb[row * 32 + slot * 8];
        }
        if (s1) stage(T + 2);
        __builtin_amdgcn_s_barrier();
        asm volatile("s_waitcnt lgkmcnt(0)" ::: "memory");
        __builtin_amdgcn_sched_barrier(0);
        __builtin_amdgcn_s_setprio(1);
#pragma unroll
        for (int m = 0; m < 8; ++m)
#pragma unroll
            for (int n = 0; n < 4; ++n)
                acc[m][n] = __builtin_amdgcn_mfma_f32_16x16x32_bf16(af[m], bq[n], acc[m][n], 0, 0, 0);
        __builtin_amdgcn_s_setprio(0);
        // boundary vmcnt + barrier placed by caller
    };

    constexpr int NT = KDIM / 32;                 // 32
    stage(0); stage(1);
    asm volatile("s_waitcnt vmcnt(6)" ::: "memory");     // tile 0 landed
    __builtin_amdgcn_s_barrier();
    __builtin_amdgcn_sched_barrier(0);

    for (int T = 0; T < NT - 2; ++T) {
        tile(T, true);
        asm volatile("s_waitcnt vmcnt(6)" ::: "memory"); // T+1 landed
        __builtin_amdgcn_s_barrier();
        __builtin_amdgcn_sched_barrier(0);
    }
    tile(NT - 2, false);
    asm volatile("s_waitcnt vmcnt(0)" ::: "memory");     // NT-1 landed
    __builtin_amdgcn_s_barrier();
    __builtin_amdgcn_sched_barrier(0);
    tile(NT - 1, false);
    __syncthreads();                                     // LDS reuse below

    // ---------------- epilogues (LDS-routed, coalesced stores) ----------------
    if (MODE == 0) {
        unsigned short* cbf = smem;                      // [128][264] bf16, one pass (66KB)
        const bool isQ = (n0 < D_), isK = (n0 >= D_ && n0 < 2*D_);
        const float scale = isQ ? 0.125f : 1.0f;
        unsigned short* buf = isQ ? qf : (isK ? kf : vf);
        const int b = m0 >> 12, l0 = m0 & 4095;
        const int h0 = (n0 & 1023) >> 6;
#pragma unroll
        for (int n = 0; n < 4; ++n) {
            int cl = w*64 + n*16 + lr;
            float bv = bias[n0 + cl];
#pragma unroll
            for (int m = 0; m < 8; ++m)
#pragma unroll
                for (int q = 0; q < 4; ++q) {
                    int rl = m*16 + lg*4 + q;
                    float val = (acc[m][n][q] + bv) * scale;
                    float fv = (isQ || isK)
                               ? ((val > 0.f ? val : __expf(val) - 1.f) + EPS_FEAT)
                               : val;
                    cbf[rl * 264 + cl] = f2bf(fv);
                }
        }
        __syncthreads();
#pragma unroll
        for (int hh = 0; hh < 4; ++hh) {
            unsigned short* dst = buf + (((size_t)(b * H_ + h0 + hh)) * L_ + l0) * E_;
#pragma unroll
            for (int i = 0; i < 4; ++i) {
                int c = i*256 + t, row = c >> 3, ch = c & 7;
                uint4 v = *(const uint4*)&cbf[row * 264 + hh*64 + ch*8];
                *(uint4*)&dst[row * 64 + ch*8] = v;
            }
        }
    } else {
        float* cfl = (float*)smem;                       // [64][260] f32, 2 passes
#pragma unroll
        for (int p = 0; p < 2; ++p) {
#pragma unroll
            for (int n = 0; n < 4; ++n) {
                int cl = w*64 + n*16 + lr;
                float bv = bias[n0 + cl];
#pragma unroll
                for (int mm = 0; mm < 4; ++mm)
#pragma unroll
                    for (int q = 0; q < 4; ++q) {
                        int rl = mm*16 + lg*4 + q;
                        cfl[rl * 260 + cl] = acc[p*4 + mm][n][q] + bv;
                    }
            }
            __syncthreads();
#pragma unroll
            for (int i = 0; i < 16; ++i) {
                int c = i*256 + t, row = c >> 6, ch = c & 63;
                float4 v = *(const float4*)&cfl[row * 260 + ch*4];
                *(float4*)&outF[(size_t)(m0 + p*64 + row) * NDIM + n0 + ch*4] = v;
            }
            __syncthreads();
        }
    }
}

// ---------------- chunk KV (TRANSPOSED state): KVT_c[f][e] = sum_l V[l][f] K[l][e] ----------------
// bf16 output (prefix accumulates in f32). ksum via Vt ones-row, f32 out.

__global__ __launch_bounds__(256) void chunk_kv(
    const unsigned short* __restrict__ kf, const unsigned short* __restrict__ vf,
    unsigned short* __restrict__ kvout, float* __restrict__ ksout)
{
    constexpr int LDK = 136;                 // 128 + 8 pad
    __shared__ unsigned short Kt[64 * LDK];  // K^T : [e][l]
    __shared__ unsigned short Vt[80 * LDK];  // V^T : [f][l], row 64 = ones (ksum trick)

    int t = threadIdx.x, lane = t & 63, w = t >> 6;
    int bid = blockIdx.x;                    // bh*NC + c
    const unsigned short* kp = kf + (size_t)bid * CHK * E_;
    const unsigned short* vp = vf + (size_t)bid * CHK * E_;

#pragma unroll
    for (int it = 0; it < 4; ++it) {
        int s = it * 256 + t;                // 0..1023  (16B granules of 128x64)
        int rl = s >> 3, e0 = (s & 7) << 3;
        uint4 kv8 = *(const uint4*)(kp + s * 8);
        uint4 vv8 = *(const uint4*)(vp + s * 8);
        unsigned int kw[4] = {kv8.x, kv8.y, kv8.z, kv8.w};
        unsigned int vw[4] = {vv8.x, vv8.y, vv8.z, vv8.w};
#pragma unroll
        for (int jw = 0; jw < 4; ++jw) {
            Kt[(e0 + 2*jw    ) * LDK + rl] = (unsigned short)(kw[jw] & 0xFFFF);
            Kt[(e0 + 2*jw + 1) * LDK + rl] = (unsigned short)(kw[jw] >> 16);
            Vt[(e0 + 2*jw    ) * LDK + rl] = (unsigned short)(vw[jw] & 0xFFFF);
            Vt[(e0 + 2*jw + 1) * LDK + rl] = (unsigned short)(vw[jw] >> 16);
        }
    }
    if (t < 128) Vt[64 * LDK + t] = 0x3F80;  // bf16 1.0
    for (int i = t; i < 15 * LDK; i += 256) Vt[65 * LDK + i] = 0;
    __syncthreads();

    int lr = lane & 15, lg = lane >> 4;
    f32x4 acc[4] = {};
    f32x4 accE[4] = {};
#pragma unroll
    for (int ks = 0; ks < 4; ++ks) {
        bf16x8 a = *(const bf16x8*)&Vt[(w*16 + lr) * LDK + ks*32 + lg*8];
#pragma unroll
        for (int n = 0; n < 4; ++n) {
            bf16x8 b = *(const bf16x8*)&Kt[(n*16 + lr) * LDK + ks*32 + lg*8];
            acc[n] = __builtin_amdgcn_mfma_f32_16x16x32_bf16(a, b, acc[n], 0, 0, 0);
        }
    }
    if (w == 0) {
#pragma unroll
        for (int ks = 0; ks < 4; ++ks) {
            bf16x8 a = *(const bf16x8*)&Vt[(64 + lr) * LDK + ks*32 + lg*8];
#pragma unroll
            for (int n = 0; n < 4; ++n) {
                bf16x8 b = *(const bf16x8*)&Kt[(n*16 + lr) * LDK + ks*32 + lg*8];
                accE[n] = __builtin_amdgcn_mfma_f32_16x16x32_bf16(a, b, accE[n], 0, 0, 0);
            }
        }
    }
    unsigned short* kvo = kvout + (size_t)bid * E_ * E_;   // [f][e]
#pragma unroll
    for (int n = 0; n < 4; ++n)
#pragma unroll
        for (int q = 0; q < 4; ++q) {
            int f = w*16 + lg*4 + q, e = n*16 + lr;
            kvo[f * 64 + e] = f2bf(acc[n][q]);
        }
    if (w == 0 && lg == 0) {
#pragma unroll
        for (int n = 0; n < 4; ++n)
            ksout[(size_t)bid * 64 + n*16 + lr] = accE[n][0];   // row 64 = ksum
    }
}

// ---------------- exclusive prefix over chunks (per bh), bf16 in/out ----------------

__global__ __launch_bounds__(256) void prefix_kv(
    const uint2* __restrict__ kvin, const float* __restrict__ ks,
    uint2* __restrict__ kvb, unsigned short* __restrict__ ksb)
{
    int bh = blockIdx.y, part = blockIdx.x, t = threadIdx.x;
    int idx = part * 256 + t;                 // uint2 index (4 bf16) within 1024/chunk
    float st0 = 0.f, st1 = 0.f, st2 = 0.f, st3 = 0.f;
    for (int c = 0; c < NC; ++c) {
        size_t o = ((size_t)bh * NC + c) * 1024 + idx;
        uint2 tmp = kvin[o];
        kvb[o] = make_uint2(
            (unsigned int)f2bf(st0) | ((unsigned int)f2bf(st1) << 16),
            (unsigned int)f2bf(st2) | ((unsigned int)f2bf(st3) << 16));
        union { unsigned int u; float f; } cv;
        cv.u = (tmp.x & 0xFFFFu) << 16; st0 += cv.f;
        cv.u = tmp.x & 0xFFFF0000u;     st1 += cv.f;
        cv.u = (tmp.y & 0xFFFFu) << 16; st2 += cv.f;
        cv.u = tmp.y & 0xFFFF0000u;     st3 += cv.f;
    }
    if (part == 0 && t < 64) {
        float s0 = 0.f;
        for (int c = 0; c < NC; ++c) {
            float tmp = ks[((size_t)bh * NC + c) * 64 + t];
            ksb[((size_t)bh * NC + c) * 64 + t] = f2bf(s0);
            s0 += tmp;
        }
    }
}

// ---------------- attention output per (bh, chunk) ----------------
// LDS 69KB -> 2 blocks/CU. Wave w owns row-blocks {w, 7-w} (balanced causal).

__global__ __launch_bounds__(256, 2) void attn_out(
    const unsigned short* __restrict__ qf, const unsigned short* __restrict__ kf,
    const unsigned short* __restrict__ vf, const unsigned short* __restrict__ kvb,
    const unsigned short* __restrict__ ksb, unsigned short* __restrict__ attn)
{
    constexpr int LK = 72;    // K stride (64+8)
    constexpr int LV = 136;   // Vt & S stride (128+8)
    __shared__ unsigned short Ks[128 * LK];   // 18.0 KB
    __shared__ unsigned short Vt[64 * LV];    // 17.0 KB
    __shared__ unsigned short Ss[128 * LV];   // 34.0 KB

    int t = threadIdx.x, lane = t & 63, w = t >> 6;
    int bid = blockIdx.x;
    int bh = bid >> 5, c = bid & 31;
    const unsigned short* qp = qf + (size_t)bid * CHK * E_;
    const unsigned short* kp = kf + (size_t)bid * CHK * E_;
    const unsigned short* vp = vf + (size_t)bid * CHK * E_;
    const unsigned short* kvp = kvb + (size_t)bid * 4096;   // [f][e]

    int lr = lane & 15, lg = lane >> 4;
    const int jsel[2] = {w, 7 - w};

    // Q frags for this wave's two row-blocks (global, coalesced 64B rows)
    bf16x8 aq[2][2];
#pragma unroll
    for (int mi = 0; mi < 2; ++mi)
#pragma unroll
        for (int ks = 0; ks < 2; ++ks)
            aq[mi][ks] = *(const bf16x8*)(qp + (jsel[mi]*16 + lr) * 64 + ks*32 + lg*8);

#pragma unroll
    for (int it = 0; it < 4; ++it) {
        int s = it * 256 + t;
        int r = s >> 3, e0 = (s & 7) << 3;
        uint4 kv = *(const uint4*)(kp + s * 8);
        uint4 vv = *(const uint4*)(vp + s * 8);
        *(uint4*)&Ks[r * LK + e0] = kv;
        unsigned int vw[4] = {vv.x, vv.y, vv.z, vv.w};
#pragma unroll
        for (int jw = 0; jw < 4; ++jw) {
            Vt[(e0 + 2*jw    ) * LV + r] = (unsigned short)(vw[jw] & 0xFFFF);
            Vt[(e0 + 2*jw + 1) * LV + r] = (unsigned short)(vw[jw] >> 16);
        }
    }
    // den B-rows in regs: only lr==0 lanes hold data (b-row 64)
    bf16x8 zfrag = {0,0,0,0,0,0,0,0};
    bf16x8 bone = zfrag, bks[2] = {zfrag, zfrag};
    if (lr == 0) {
#pragma unroll
        for (int j = 0; j < 8; ++j) bone[j] = (short)0x3F80;
        bks[0] = *(const bf16x8*)&ksb[(size_t)bid * 64 + lg*8];
        bks[1] = *(const bf16x8*)&ksb[(size_t)bid * 64 + 32 + lg*8];
    }
    __syncthreads();

    // S-phase: wave w writes row-blocks jsel[0..1]
#pragma unroll
    for (int mi = 0; mi < 2; ++mi) {
        int j = jsel[mi];
        int rbase = j * 16;
        int jbmax = j | 1;                 // PV reads cols up to block (j|1)
        for (int jb = 0; jb <= jbmax; ++jb) {
            if (jb <= j) {
                f32x4 sacc = {};
                bf16x8 b0 = *(const bf16x8*)&Ks[(jb*16 + lr) * LK + lg*8];
                bf16x8 b1 = *(const bf16x8*)&Ks[(jb*16 + lr) * LK + 32 + lg*8];
                sacc = __builtin_amdgcn_mfma_f32_16x16x32_bf16(aq[mi][0], b0, sacc, 0, 0, 0);
                sacc = __builtin_amdgcn_mfma_f32_16x16x32_bf16(aq[mi][1], b1, sacc, 0, 0, 0);
#pragma unroll
                for (int q = 0; q < 4; ++q) {
                    int r = rbase + lg*4 + q;
                    int jj = jb*16 + lr;
                    Ss[r * LV + jj] = (jj <= r) ? f2bf(sacc[q]) : (unsigned short)0;
                }
            } else {
#pragma unroll
                for (int q = 0; q < 4; ++q) {
                    int r = rbase + lg*4 + q;
                    Ss[r * LV + jb*16 + lr] = 0;
                }
            }
        }
    }
    // no barrier needed: each wave reads only its own S rows below

    f32x4 oacc[2][5] = {};
#pragma unroll
    for (int mi = 0; mi < 2; ++mi) {
        int j = jsel[mi];
        int rbase = j * 16;
        // inter-chunk: Q @ KV_state (K-dim 64); B frags from global [f][e]
#pragma unroll
        for (int ks = 0; ks < 2; ++ks) {
            bf16x8 a = aq[mi][ks];
#pragma unroll
            for (int n = 0; n < 4; ++n) {
                bf16x8 b = *(const bf16x8*)&kvp[(n*16 + lr) * 64 + ks*32 + lg*8];
                oacc[mi][n] = __builtin_amdgcn_mfma_f32_16x16x32_bf16(a, b, oacc[mi][n], 0, 0, 0);
            }
            oacc[mi][4] = __builtin_amdgcn_mfma_f32_16x16x32_bf16(a, bks[ks], oacc[mi][4], 0, 0, 0);
        }
        // intra-chunk: S @ V  (k-blocks ks <= j>>1 nonzero)
        for (int ks = 0; ks <= (j >> 1); ++ks) {
            bf16x8 a = *(const bf16x8*)&Ss[(rbase + lr) * LV + ks*32 + lg*8];
#pragma unroll
            for (int n = 0; n < 4; ++n) {
                bf16x8 b = *(const bf16x8*)&Vt[(n*16 + lr) * LV + ks*32 + lg*8];
                oacc[mi][n] = __builtin_amdgcn_mfma_f32_16x16x32_bf16(a, b, oacc[mi][n], 0, 0, 0);
            }
            oacc[mi][4] = __builtin_amdgcn_mfma_f32_16x16x32_bf16(a, bone, oacc[mi][4], 0, 0, 0);
        }
    }

    // den broadcast (col 64 lives in lanes with lr==0) + normalize + store
    int b_idx = bh >> 4, h_idx = bh & 15;
#pragma unroll
    for (int mi = 0; mi < 2; ++mi) {
        int rbase = jsel[mi] * 16;
        float den[4];
#pragma unroll
        for (int q = 0; q < 4; ++q)
            den[q] = __shfl(oacc[mi][4][q], lane & 48, 64) + EPS_DEN;
#pragma unroll
        for (int n = 0; n < 4; ++n) {
#pragma unroll
            for (int q = 0; q < 4; ++q) {
                int r = rbase + lg*4 + q;
                int lpos = c * CHK + r;
                int col = n*16 + lr;
                size_t dst = ((size_t)b_idx * L_ + lpos) * D_ + h_idx * 64 + col;
                attn[dst] = f2bf(oacc[mi][n][q] / den[q]);
            }
        }
    }
}

// ---------------- launcher ----------------

extern "C" void kernel_launch(void* const* d_in, const int* in_sizes, int n_in,
                              void* d_out, int out_size, void* d_ws, size_t ws_size,
                              hipStream_t stream)
{
    const float* x    = (const float*)d_in[0];
    const float* Wqkv = (const float*)d_in[1];
    const float* bqkv = (const float*)d_in[2];
    const float* Wout = (const float*)d_in[3];
    const float* bout = (const float*)d_in[4];
    float* out = (float*)d_out;

    char* ws = (char*)d_ws;
    size_t off = 0;
    auto alloc = [&](size_t bytes) { void* p = ws + off; off += (bytes + 255) & ~(size_t)255; return p; };
    unsigned short* xb  = (unsigned short*)alloc((size_t)M_ * D_ * 2);
    unsigned short* WqT = (unsigned short*)alloc((size_t)N1_ * D_ * 2);
    unsigned short* WoT = (unsigned short*)alloc((size_t)D_ * D_ * 2);
    unsigned short* qfb = (unsigned short*)alloc((size_t)M_ * D_ * 2);
    unsigned short* kfb = (unsigned short*)alloc((size_t)M_ * D_ * 2);
    unsigned short* vfb = (unsigned short*)alloc((size_t)M_ * D_ * 2);
    unsigned short* kvw = (unsigned short*)alloc((size_t)BH * NC * E_ * E_ * 2);
    float* ksw = (float*)alloc((size_t)BH * NC * E_ * 4);
    unsigned short* kvb = (unsigned short*)alloc((size_t)BH * NC * E_ * E_ * 2);
    unsigned short* ksb = (unsigned short*)alloc((size_t)BH * NC * E_ * 2);
    unsigned short* attn = xb;   // alias: x_bf16 is dead after gemm<0>

    prep<<<16384 + 3072 + 1024, 256, 0, stream>>>(x, Wqkv, Wout, xb, WqT, WoT);

    gemm128<0, D_, N1_><<<dim3(N1_ / 256, M_ / 128), 256, 0, stream>>>(
        xb, WqT, bqkv, nullptr, qfb, kfb, vfb);

    chunk_kv<<<BH * NC, 256, 0, stream>>>(kfb, vfb, kvw, ksw);
    prefix_kv<<<dim3(4, BH), 256, 0, stream>>>((const uint2*)kvw, ksw, (uint2*)kvb, ksb);
    attn_out<<<BH * NC, 256, 0, stream>>>(qfb, kfb, vfb, kvb, ksb, attn);

    gemm128<1, D_, D_><<<dim3(D_ / 256, M_ / 128), 256, 0, stream>>>(
        attn, WoT, bout, out, nullptr, nullptr, nullptr);
}